// Round 1
// baseline (176.976 us; speedup 1.0000x reference)
//
#include <hip/hip_runtime.h>
#include <hip/hip_bf16.h>
#include <math.h>

// Problem constants (from reference setup_inputs)
#define BB 32
#define DD 64
#define HH 32
#define WW 32
#define NN (BB * HH * WW)   // 32768 rows
#define KK 1024             // codes
#define HW (HH * WW)        // 1024
#define NQ (BB * DD * HH * WW)  // 2097152 quantized elements

#define EPS_F 1e-12f
#define PERP_EPS_F 1e-10f

// ---------------------------------------------------------------------------
// Kernel 1: per-code squared norms  cnorm[j] = sum_d c[j][d]^2
// ---------------------------------------------------------------------------
__global__ __launch_bounds__(256) void k_cnorm(const float* __restrict__ cb,
                                               float* __restrict__ cnorm) {
    int j = blockIdx.x * 256 + threadIdx.x;
    if (j >= KK) return;
    const float4* row = reinterpret_cast<const float4*>(cb + (size_t)j * DD);
    float s = 0.0f;
#pragma unroll
    for (int i = 0; i < DD / 4; ++i) {
        float4 v = row[i];
        s += v.x * v.x + v.y * v.y + v.z * v.z + v.w * v.w;
    }
    cnorm[j] = s;
}

// ---------------------------------------------------------------------------
// Kernel 2: argmin over codes of (||c||^2 - 2 x.c) per row, + histogram.
// Block = 256 threads, owns 64 consecutive rows x all 1024 codes.
// Thread (tx in [0,16), ty in [0,16)) computes 4 rows x 4 codes per tile.
// ---------------------------------------------------------------------------
__global__ __launch_bounds__(256) void k_argmin(const float* __restrict__ inp,
                                                const float* __restrict__ cb,
                                                const float* __restrict__ cnorm,
                                                int* __restrict__ min_idx,
                                                unsigned int* __restrict__ counts) {
    __shared__ __align__(16) float xs[64 * 64];  // [d][nl]  (d-major like NCHW)
    __shared__ __align__(16) float cs[64 * 64];  // [d][jl]  (transposed tile)
    __shared__ float md[64 * 16];                // merge: dist per [row][tx]
    __shared__ int   mi[64 * 16];                // merge: idx  per [row][tx]

    const int tid = threadIdx.x;
    const int blk = blockIdx.x;
    const int nbase = blk * 64;
    const int b = nbase >> 10;        // 64 rows never cross a batch boundary
    const int hwbase = nbase & 1023;  // nor an HW boundary (64 | 1024)
    const float* xg = inp + (size_t)b * (DD * HW) + hwbase;  // xg[d*HW + nl]

    // Stage x-tile: inputs are NCHW -> already [d][nl] layout, fully coalesced.
#pragma unroll
    for (int i = 0; i < 16; ++i) {
        int idx = i * 256 + tid;  // idx = d*64 + nl
        xs[idx] = xg[(idx >> 6) * HW + (idx & 63)];
    }

    const int tx = tid & 15;
    const int ty = tid >> 4;
    const int w = tid >> 6;     // wave id 0..3
    const int lane = tid & 63;

    float minv[4];
    int mini[4];
#pragma unroll
    for (int r = 0; r < 4; ++r) { minv[r] = 3.4e38f; mini[r] = 0; }

    for (int t = 0; t < 16; ++t) {
        __syncthreads();  // protect cs (and xs on t==0) before overwrite/use
        const int jbase = t * 64;
        // Stage code tile transposed: cs[d][jl] = cb[jbase+jl][d].
        // Wave w writes d-planes {i*4+w}; LDS writes are lane-consecutive.
#pragma unroll
        for (int i = 0; i < 16; ++i) {
            int d = i * 4 + w;
            cs[d * 64 + lane] = cb[(size_t)(jbase + lane) * DD + d];
        }
        __syncthreads();

        float acc[4][4];
#pragma unroll
        for (int r = 0; r < 4; ++r)
#pragma unroll
            for (int c = 0; c < 4; ++c) acc[r][c] = 0.0f;

#pragma unroll 16
        for (int d = 0; d < 64; ++d) {
            const float4 xv = *reinterpret_cast<const float4*>(&xs[d * 64 + ty * 4]);
            const float4 cv = *reinterpret_cast<const float4*>(&cs[d * 64 + tx * 4]);
            acc[0][0] = fmaf(xv.x, cv.x, acc[0][0]);
            acc[0][1] = fmaf(xv.x, cv.y, acc[0][1]);
            acc[0][2] = fmaf(xv.x, cv.z, acc[0][2]);
            acc[0][3] = fmaf(xv.x, cv.w, acc[0][3]);
            acc[1][0] = fmaf(xv.y, cv.x, acc[1][0]);
            acc[1][1] = fmaf(xv.y, cv.y, acc[1][1]);
            acc[1][2] = fmaf(xv.y, cv.z, acc[1][2]);
            acc[1][3] = fmaf(xv.y, cv.w, acc[1][3]);
            acc[2][0] = fmaf(xv.z, cv.x, acc[2][0]);
            acc[2][1] = fmaf(xv.z, cv.y, acc[2][1]);
            acc[2][2] = fmaf(xv.z, cv.z, acc[2][2]);
            acc[2][3] = fmaf(xv.z, cv.w, acc[2][3]);
            acc[3][0] = fmaf(xv.w, cv.x, acc[3][0]);
            acc[3][1] = fmaf(xv.w, cv.y, acc[3][1]);
            acc[3][2] = fmaf(xv.w, cv.z, acc[3][2]);
            acc[3][3] = fmaf(xv.w, cv.w, acc[3][3]);
        }

        const float4 cn4 = *reinterpret_cast<const float4*>(&cnorm[jbase + tx * 4]);
        const float cnf[4] = {cn4.x, cn4.y, cn4.z, cn4.w};
#pragma unroll
        for (int r = 0; r < 4; ++r) {
#pragma unroll
            for (int c = 0; c < 4; ++c) {
                float dist = cnf[c] - 2.0f * acc[r][c];
                int j = jbase + tx * 4 + c;
                // ascending t, ascending c, strict '<' => first-min kept
                if (dist < minv[r]) { minv[r] = dist; mini[r] = j; }
            }
        }
    }

    // Cross-thread merge over tx (16 code-threads per row)
#pragma unroll
    for (int r = 0; r < 4; ++r) {
        md[(ty * 4 + r) * 16 + tx] = minv[r];
        mi[(ty * 4 + r) * 16 + tx] = mini[r];
    }
    __syncthreads();
    if (tid < 64) {
        float best = md[tid * 16 + 0];
        int bi = mi[tid * 16 + 0];
#pragma unroll
        for (int q = 1; q < 16; ++q) {
            float dv = md[tid * 16 + q];
            int iv = mi[tid * 16 + q];
            if (dv < best || (dv == best && iv < bi)) { best = dv; bi = iv; }
        }
        min_idx[nbase + tid] = bi;
        atomicAdd(&counts[bi], 1u);
    }
}

// ---------------------------------------------------------------------------
// Kernel 3: norms, noise injection, NCHW output.
// Block = 256 threads, 64 rows. 4 lanes cooperate per row on the reductions.
// ---------------------------------------------------------------------------
__global__ __launch_bounds__(256) void k_out(const float* __restrict__ inp,
                                             const float* __restrict__ cb,
                                             const float* __restrict__ noise,
                                             const int* __restrict__ min_idx,
                                             float* __restrict__ out) {
    __shared__ __align__(16) float xs[64 * 64];   // [d][nl]
    __shared__ __align__(16) float ns[64 * 68];   // [nl][d], padded stride 68
    __shared__ float sscale[64];

    const int tid = threadIdx.x;
    const int blk = blockIdx.x;
    const int nbase = blk * 64;
    const int b = nbase >> 10;
    const int hwbase = nbase & 1023;
    const float* xg = inp + (size_t)b * (DD * HW) + hwbase;

#pragma unroll
    for (int i = 0; i < 16; ++i) {
        int idx = i * 256 + tid;  // = d*64 + nl
        xs[idx] = xg[(idx >> 6) * HW + (idx & 63)];
    }
#pragma unroll
    for (int i = 0; i < 16; ++i) {
        int idx = i * 256 + tid;
        int nl = idx >> 6, d = idx & 63;
        ns[nl * 68 + d] = noise[(size_t)(nbase + nl) * DD + d];  // coalesced
    }
    __syncthreads();

    // Phase A: per-row sums. thread -> (row nl, quarter q of dims)
    const int nl = tid >> 2;
    const int q = tid & 3;
    const int j = min_idx[nbase + nl];
    const float* cr = cb + (size_t)j * DD;
    float sb = 0.0f, sn = 0.0f;
#pragma unroll
    for (int dd = 0; dd < 16; ++dd) {
        int d = q * 16 + dd;
        float xv = xs[d * 64 + nl];
        float cv = cr[d];
        float nv = ns[nl * 68 + d];
        float diff = xv - cv;
        sb = fmaf(diff, diff, sb);
        sn = fmaf(nv, nv, sn);
    }
    // reduce the 4 partials per row (q lives in lane bits 0..1)
    sb += __shfl_xor(sb, 1); sb += __shfl_xor(sb, 2);
    sn += __shfl_xor(sn, 1); sn += __shfl_xor(sn, 2);
    if (q == 0) sscale[nl] = sqrtf(sb) / sqrtf(sn) + EPS_F;
    __syncthreads();

    // Phase B: quantized = x + scale*noise, written NCHW-coalesced.
#pragma unroll
    for (int i = 0; i < 16; ++i) {
        int idx = i * 256 + tid;  // = d*64 + nl
        int d = idx >> 6, nl2 = idx & 63;
        out[(size_t)(b * DD + d) * HW + hwbase + nl2] =
            xs[idx] + sscale[nl2] * ns[nl2 * 68 + d];
    }
}

// ---------------------------------------------------------------------------
// Kernel 4: perplexity from the usage histogram. One block, 1024 threads.
// ---------------------------------------------------------------------------
__global__ __launch_bounds__(1024) void k_perp(const unsigned int* __restrict__ counts,
                                               float* __restrict__ out) {
    __shared__ float red[16];
    const int tid = threadIdx.x;
    const int lane = tid & 63;
    float p = (float)counts[tid] * (1.0f / (float)NN);
    float t = p * logf(p + PERP_EPS_F);
#pragma unroll
    for (int off = 32; off > 0; off >>= 1) t += __shfl_down(t, off);
    if (lane == 0) red[tid >> 6] = t;
    __syncthreads();
    if (tid == 0) {
        float s = 0.0f;
#pragma unroll
        for (int i = 0; i < 16; ++i) s += red[i];
        out[0] = expf(-s);
    }
}

// ---------------------------------------------------------------------------
extern "C" void kernel_launch(void* const* d_in, const int* in_sizes, int n_in,
                              void* d_out, int out_size, void* d_ws, size_t ws_size,
                              hipStream_t stream) {
    (void)in_sizes; (void)n_in; (void)out_size; (void)ws_size;
    const float* inp   = (const float*)d_in[0];   // (B,D,H,W)
    const float* cb    = (const float*)d_in[1];   // (K,D)
    const float* noise = (const float*)d_in[2];   // (N,D)
    float* out = (float*)d_out;                   // [NQ quantized][1 perplexity]

    char* ws = (char*)d_ws;
    float*        cnorm   = (float*)ws;                       // 1024 f32 (4 KB)
    int*          min_idx = (int*)(ws + 4096);                // 32768 i32 (128 KB)
    unsigned int* counts  = (unsigned int*)(ws + 4096 + 131072);  // 1024 u32

    hipMemsetAsync(counts, 0, KK * sizeof(unsigned int), stream);
    k_cnorm<<<KK / 256, 256, 0, stream>>>(cb, cnorm);
    k_argmin<<<NN / 64, 256, 0, stream>>>(inp, cb, cnorm, min_idx, counts);
    k_out<<<NN / 64, 256, 0, stream>>>(inp, cb, noise, min_idx, out);
    k_perp<<<1, 1024, 0, stream>>>(counts, out + NQ);
}

// Round 2
// 118.242 us; speedup vs baseline: 1.4967x; 1.4967x over previous
//
#include <hip/hip_runtime.h>
#include <hip/hip_bf16.h>
#include <math.h>

// Problem constants (from reference setup_inputs)
#define BB 32
#define DD 64
#define HH 32
#define WW 32
#define NN (BB * HH * WW)       // 32768 rows
#define KK 1024                 // codes
#define HW (HH * WW)            // 1024
#define NQ (BB * DD * HH * WW)  // 2097152 quantized elements

#define EPS_F 1e-12f
#define PERP_EPS_F 1e-10f

typedef __attribute__((ext_vector_type(8))) __bf16 bf16x8;
typedef __attribute__((ext_vector_type(4))) float f32x4;

// fp32 -> bf16 round-to-nearest-even, bit-level (avoids hip_bf16 API drift)
static __device__ __forceinline__ unsigned short f2bf(float f) {
    union { float f; unsigned int u; } c;
    c.f = f;
    unsigned int r = c.u + 0x7FFFu + ((c.u >> 16) & 1u);
    return (unsigned short)(r >> 16);
}

// ---------------------------------------------------------------------------
// Kernel 1: codes fp32 -> bf16 (same [j][d] layout) + per-code squared norms.
// One thread per code row. grid 4 x 256.
// ---------------------------------------------------------------------------
__global__ __launch_bounds__(256) void k_prep(const float* __restrict__ cb,
                                              unsigned short* __restrict__ cbh,
                                              float* __restrict__ cnorm) {
    int j = blockIdx.x * 256 + threadIdx.x;
    if (j >= KK) return;
    const float4* src = reinterpret_cast<const float4*>(cb + (size_t)j * DD);
    ushort4* dst = reinterpret_cast<ushort4*>(cbh + (size_t)j * DD);
    float s = 0.0f;
#pragma unroll
    for (int i = 0; i < DD / 4; ++i) {
        float4 v = src[i];
        s += v.x * v.x + v.y * v.y + v.z * v.z + v.w * v.w;
        ushort4 u;
        u.x = f2bf(v.x); u.y = f2bf(v.y); u.z = f2bf(v.z); u.w = f2bf(v.w);
        dst[i] = u;
    }
    cnorm[j] = s;
}

// ---------------------------------------------------------------------------
// Kernel 2: MFMA argmin.  dist = ||c||^2 - 2 x.c  (||x||^2 row-constant).
// 256 blocks x 256 threads; wave w owns rows [blk*128 + w*32, +32).
// A (x rows, bf16) lives in registers for the whole kernel; B-frags stream
// from global bf16 codes (L2-resident) -> no barriers in the K-loop.
// ---------------------------------------------------------------------------
__global__ __launch_bounds__(256) void k_argmin(const float* __restrict__ inp,
                                                const unsigned short* __restrict__ cbh,
                                                const float* __restrict__ cnorm,
                                                int* __restrict__ min_idx,
                                                unsigned int* __restrict__ counts) {
    __shared__ __align__(16) unsigned short xls[128 * 72];  // [row][d], stride 72 (144B, 16B-aligned)

    const int tid = threadIdx.x;
    const int nbase = blockIdx.x * 128;
    const int b = nbase >> 10;        // 128 | 1024 so no batch/HW crossing
    const int hwbase = nbase & 1023;
    const float* xg = inp + (size_t)b * (DD * HW) + hwbase;

    // Stage x: global is [d][hw] (NCHW) -> coalesced reads, transposed bf16 LDS store.
#pragma unroll
    for (int i = 0; i < 32; ++i) {
        int idx = i * 256 + tid;       // idx = d*128 + r
        int d = idx >> 7, r = idx & 127;
        xls[r * 72 + d] = f2bf(xg[d * HW + r]);
    }
    __syncthreads();

    const int lane = tid & 63;
    const int w = tid >> 6;        // wave id: rows w*32..w*32+31
    const int col = lane & 15;     // MFMA col / A-row-within-tile index
    const int quad = lane >> 4;    // k-group (A/B), row-group (C)
    const int rbase = w * 32;

    // A fragments: A[m=lane&15][k=quad*8+j]; 2 row-tiles x 2 k-halves.
    const bf16x8 a00 = *reinterpret_cast<const bf16x8*>(&xls[(rbase + col) * 72 + quad * 8]);
    const bf16x8 a01 = *reinterpret_cast<const bf16x8*>(&xls[(rbase + col) * 72 + 32 + quad * 8]);
    const bf16x8 a10 = *reinterpret_cast<const bf16x8*>(&xls[(rbase + 16 + col) * 72 + quad * 8]);
    const bf16x8 a11 = *reinterpret_cast<const bf16x8*>(&xls[(rbase + 16 + col) * 72 + 32 + quad * 8]);

    float minv[8];
    int mint[8];
#pragma unroll
    for (int s = 0; s < 8; ++s) { minv[s] = 3.4e38f; mint[s] = 0; }

    // B-frag lane base: code row (jt*16 + col), contiguous 8 d per quad.
    const unsigned short* bp = cbh + (size_t)col * DD + quad * 8;

    bf16x8 bcur[8], bnxt[8];
    float cncur[4], cnnxt[4];
    // preload group 0 (tiles 0..3)
#pragma unroll
    for (int t = 0; t < 4; ++t) {
        bcur[2 * t]     = *reinterpret_cast<const bf16x8*>(bp + (size_t)t * 16 * DD);
        bcur[2 * t + 1] = *reinterpret_cast<const bf16x8*>(bp + (size_t)t * 16 * DD + 32);
        cncur[t] = cnorm[t * 16 + col];
    }

    for (int g = 0; g < 16; ++g) {
        const int gn = (g + 1) & 15;  // wraps on last iter (harmless re-read of group 0)
        // prefetch next group's B-frags + cnorms (lands during this group's MFMA+epilogue)
#pragma unroll
        for (int t = 0; t < 4; ++t) {
            const size_t off = ((size_t)(gn * 4 + t) * 16) * DD;
            bnxt[2 * t]     = *reinterpret_cast<const bf16x8*>(bp + off);
            bnxt[2 * t + 1] = *reinterpret_cast<const bf16x8*>(bp + off + 32);
            cnnxt[t] = cnorm[(gn * 4 + t) * 16 + col];
        }
#pragma unroll
        for (int t = 0; t < 4; ++t) {
            const int jt = g * 4 + t;
            f32x4 acc0 = {0.f, 0.f, 0.f, 0.f};
            f32x4 acc1 = {0.f, 0.f, 0.f, 0.f};
            acc0 = __builtin_amdgcn_mfma_f32_16x16x32_bf16(a00, bcur[2 * t], acc0, 0, 0, 0);
            acc0 = __builtin_amdgcn_mfma_f32_16x16x32_bf16(a01, bcur[2 * t + 1], acc0, 0, 0, 0);
            acc1 = __builtin_amdgcn_mfma_f32_16x16x32_bf16(a10, bcur[2 * t], acc1, 0, 0, 0);
            acc1 = __builtin_amdgcn_mfma_f32_16x16x32_bf16(a11, bcur[2 * t + 1], acc1, 0, 0, 0);
            const float cn = cncur[t];
#pragma unroll
            for (int r = 0; r < 4; ++r) {
                float d0 = fmaf(-2.0f, acc0[r], cn);
                if (d0 < minv[r]) { minv[r] = d0; mint[r] = jt; }      // ascending jt + '<' => first min
                float d1 = fmaf(-2.0f, acc1[r], cn);
                if (d1 < minv[4 + r]) { minv[4 + r] = d1; mint[4 + r] = jt; }
            }
        }
#pragma unroll
        for (int i = 0; i < 8; ++i) bcur[i] = bnxt[i];
#pragma unroll
        for (int t = 0; t < 4; ++t) cncur[t] = cnnxt[t];
    }

    // Cross-lane reduce: each row's 16 candidates live across the quad's 16 lanes.
#pragma unroll
    for (int s = 0; s < 8; ++s) {
        float v = minv[s];
        int j = mint[s] * 16 + col;
#pragma unroll
        for (int off = 1; off < 16; off <<= 1) {
            float ov = __shfl_xor(v, off);
            int oj = __shfl_xor(j, off);
            if (ov < v || (ov == v && oj < j)) { v = ov; j = oj; }  // lowest index on tie
        }
        if (col == 0) {
            const int row = nbase + rbase + (s >> 2) * 16 + quad * 4 + (s & 3);
            min_idx[row] = j;
            atomicAdd(&counts[j], 1u);
        }
    }
}

// ---------------------------------------------------------------------------
// Kernel 3: exact fp32 norms, noise injection, NCHW output.
// Block = 256 threads, 64 rows. 4 lanes cooperate per row on the reductions.
// ---------------------------------------------------------------------------
__global__ __launch_bounds__(256) void k_out(const float* __restrict__ inp,
                                             const float* __restrict__ cb,
                                             const float* __restrict__ noise,
                                             const int* __restrict__ min_idx,
                                             float* __restrict__ out) {
    __shared__ __align__(16) float xs[64 * 64];   // [d][nl]
    __shared__ __align__(16) float ns[64 * 68];   // [nl][d], padded stride 68
    __shared__ float sscale[64];

    const int tid = threadIdx.x;
    const int nbase = blockIdx.x * 64;
    const int b = nbase >> 10;
    const int hwbase = nbase & 1023;
    const float* xg = inp + (size_t)b * (DD * HW) + hwbase;

#pragma unroll
    for (int i = 0; i < 16; ++i) {
        int idx = i * 256 + tid;  // = d*64 + nl
        xs[idx] = xg[(idx >> 6) * HW + (idx & 63)];
    }
#pragma unroll
    for (int i = 0; i < 16; ++i) {
        int idx = i * 256 + tid;
        int nl = idx >> 6, d = idx & 63;
        ns[nl * 68 + d] = noise[(size_t)(nbase + nl) * DD + d];  // coalesced
    }
    __syncthreads();

    const int nl = tid >> 2;
    const int q = tid & 3;
    const int j = min_idx[nbase + nl];
    const float* cr = cb + (size_t)j * DD;
    float sb = 0.0f, sn = 0.0f;
#pragma unroll
    for (int dd = 0; dd < 16; ++dd) {
        int d = q * 16 + dd;
        float xv = xs[d * 64 + nl];
        float cv = cr[d];
        float nv = ns[nl * 68 + d];
        float diff = xv - cv;
        sb = fmaf(diff, diff, sb);
        sn = fmaf(nv, nv, sn);
    }
    sb += __shfl_xor(sb, 1); sb += __shfl_xor(sb, 2);
    sn += __shfl_xor(sn, 1); sn += __shfl_xor(sn, 2);
    if (q == 0) sscale[nl] = sqrtf(sb) / sqrtf(sn) + EPS_F;
    __syncthreads();

#pragma unroll
    for (int i = 0; i < 16; ++i) {
        int idx = i * 256 + tid;  // = d*64 + nl
        int d = idx >> 6, nl2 = idx & 63;
        out[(size_t)(b * DD + d) * HW + hwbase + nl2] =
            xs[idx] + sscale[nl2] * ns[nl2 * 68 + d];
    }
}

// ---------------------------------------------------------------------------
// Kernel 4: perplexity from the usage histogram. One block, 1024 threads.
// ---------------------------------------------------------------------------
__global__ __launch_bounds__(1024) void k_perp(const unsigned int* __restrict__ counts,
                                               float* __restrict__ out) {
    __shared__ float red[16];
    const int tid = threadIdx.x;
    const int lane = tid & 63;
    float p = (float)counts[tid] * (1.0f / (float)NN);
    float t = p * logf(p + PERP_EPS_F);
#pragma unroll
    for (int off = 32; off > 0; off >>= 1) t += __shfl_down(t, off);
    if (lane == 0) red[tid >> 6] = t;
    __syncthreads();
    if (tid == 0) {
        float s = 0.0f;
#pragma unroll
        for (int i = 0; i < 16; ++i) s += red[i];
        out[0] = expf(-s);
    }
}

// ---------------------------------------------------------------------------
extern "C" void kernel_launch(void* const* d_in, const int* in_sizes, int n_in,
                              void* d_out, int out_size, void* d_ws, size_t ws_size,
                              hipStream_t stream) {
    (void)in_sizes; (void)n_in; (void)out_size; (void)ws_size;
    const float* inp   = (const float*)d_in[0];   // (B,D,H,W)
    const float* cb    = (const float*)d_in[1];   // (K,D)
    const float* noise = (const float*)d_in[2];   // (N,D)
    float* out = (float*)d_out;                   // [NQ quantized][1 perplexity]

    char* ws = (char*)d_ws;
    float*          cnorm   = (float*)ws;                         // 4 KB
    int*            min_idx = (int*)(ws + 4096);                  // 128 KB
    unsigned int*   counts  = (unsigned int*)(ws + 4096 + 131072);// 4 KB
    unsigned short* cbh     = (unsigned short*)(ws + 4096 + 131072 + 4096);  // 128 KB

    hipMemsetAsync(counts, 0, KK * sizeof(unsigned int), stream);
    k_prep<<<KK / 256, 256, 0, stream>>>(cb, cbh, cnorm);
    k_argmin<<<NN / 128, 256, 0, stream>>>(inp, cbh, cnorm, min_idx, counts);
    k_out<<<NN / 64, 256, 0, stream>>>(inp, cb, noise, min_idx, out);
    k_perp<<<1, 1024, 0, stream>>>(counts, out + NQ);
}

// Round 3
// 107.262 us; speedup vs baseline: 1.6499x; 1.1024x over previous
//
#include <hip/hip_runtime.h>
#include <hip/hip_bf16.h>
#include <math.h>

// Problem constants (from reference setup_inputs)
#define BB 32
#define DD 64
#define HH 32
#define WW 32
#define NN (BB * HH * WW)       // 32768 rows
#define KK 1024                 // codes
#define HW (HH * WW)            // 1024
#define NQ (BB * DD * HH * WW)  // 2097152 quantized elements

#define EPS_F 1e-12f
#define PERP_EPS_F 1e-10f
#define DIST_BIAS 512.0f        // makes dist strictly positive -> uint-monotonic

typedef __attribute__((ext_vector_type(8))) __bf16 bf16x8;
typedef __attribute__((ext_vector_type(8))) unsigned short u16x8;
typedef __attribute__((ext_vector_type(4))) float f32x4;

// fp32 -> bf16 round-to-nearest-even, bit-level
static __device__ __forceinline__ unsigned short f2bf(float f) {
    union { float f; unsigned int u; } c;
    c.f = f;
    unsigned int r = c.u + 0x7FFFu + ((c.u >> 16) & 1u);
    return (unsigned short)(r >> 16);
}

// ---------------------------------------------------------------------------
// Kernel 1: codes fp32 -> bf16 + (||c||^2 + 512) + zero the histogram.
// ---------------------------------------------------------------------------
__global__ __launch_bounds__(256) void k_prep(const float* __restrict__ cb,
                                              unsigned short* __restrict__ cbh,
                                              float* __restrict__ cnorm,
                                              unsigned int* __restrict__ counts) {
    int j = blockIdx.x * 256 + threadIdx.x;
    if (j >= KK) return;
    counts[j] = 0u;
    const float4* src = reinterpret_cast<const float4*>(cb + (size_t)j * DD);
    ushort4* dst = reinterpret_cast<ushort4*>(cbh + (size_t)j * DD);
    float s = 0.0f;
#pragma unroll
    for (int i = 0; i < DD / 4; ++i) {
        float4 v = src[i];
        s += v.x * v.x + v.y * v.y + v.z * v.z + v.w * v.w;
        ushort4 u;
        u.x = f2bf(v.x); u.y = f2bf(v.y); u.z = f2bf(v.z); u.w = f2bf(v.w);
        dst[i] = u;
    }
    cnorm[j] = s + DIST_BIAS;
}

// ---------------------------------------------------------------------------
// Kernel 2: MFMA argmin.  dist = (||c||^2+512) - 2 x.c  (||x||^2 row-const).
// 1024 blocks x 256 threads = 4 waves/SIMD. Block owns 32 rows; wave w
// computes all 32 rows x codes [w*256, w*256+256). B-frags stream from
// global bf16 codes (L2-resident), fully-unrolled 2-tile double buffer.
// Argmin carried as packed u32: (bits(dist+512) & ~255) | local_code_idx.
// ---------------------------------------------------------------------------
__global__ __launch_bounds__(256) void k_argmin(const float* __restrict__ inp,
                                                const unsigned short* __restrict__ cbh,
                                                const float* __restrict__ cnorm,
                                                int* __restrict__ min_idx,
                                                unsigned int* __restrict__ counts) {
    __shared__ __align__(16) unsigned short xls[32 * 72];  // [row][d], stride 72 (144 B)
    __shared__ unsigned int mg[32 * 4];                     // winner per [row][quarter]

    const int tid = threadIdx.x;
    const int nbase = blockIdx.x * 32;
    const int b = nbase >> 10;        // 32 | 1024: no batch/HW crossing
    const int hwbase = nbase & 1023;
    const float* xg = inp + (size_t)b * (DD * HW) + hwbase;

    // Stage x: thread -> (row r = tid&31, octet oct = tid>>5). Global reads are
    // lane-consecutive in r (coalesced); one 16B LDS write per thread.
    {
        const int r = tid & 31;
        const int oct = tid >> 5;  // 0..7
        u16x8 pk;
#pragma unroll
        for (int j2 = 0; j2 < 8; ++j2)
            pk[j2] = f2bf(xg[(oct * 8 + j2) * HW + r]);
        *reinterpret_cast<u16x8*>(&xls[r * 72 + oct * 8]) = pk;
    }
    __syncthreads();

    const int lane = tid & 63;
    const int w = tid >> 6;        // wave id = code quarter
    const int col = lane & 15;
    const int quad = lane >> 4;

    // A fragments: A[m=lane&15][k=quad*8+j]; 2 row-tiles x 2 k-halves, held all kernel.
    const bf16x8 a00 = *reinterpret_cast<const bf16x8*>(&xls[col * 72 + quad * 8]);
    const bf16x8 a01 = *reinterpret_cast<const bf16x8*>(&xls[col * 72 + 32 + quad * 8]);
    const bf16x8 a10 = *reinterpret_cast<const bf16x8*>(&xls[(16 + col) * 72 + quad * 8]);
    const bf16x8 a11 = *reinterpret_cast<const bf16x8*>(&xls[(16 + col) * 72 + 32 + quad * 8]);

    unsigned int minu[8];
#pragma unroll
    for (int s = 0; s < 8; ++s) minu[s] = 0xFFFFFFFFu;

    // B lane base: code row (w*256 + jt*16 + col), 8 contiguous d per quad.
    const unsigned short* bp = cbh + (size_t)(w * 256 + col) * DD + quad * 8;
    const float* cnp = cnorm + w * 256 + col;

    bf16x8 bb[2][4];
    float cn[2][2];
    // preload group 0 (tiles 0,1)
#pragma unroll
    for (int t2 = 0; t2 < 2; ++t2) {
        bb[0][t2 * 2]     = *reinterpret_cast<const bf16x8*>(bp + (size_t)(t2 * 16) * DD);
        bb[0][t2 * 2 + 1] = *reinterpret_cast<const bf16x8*>(bp + (size_t)(t2 * 16) * DD + 32);
        cn[0][t2] = cnp[t2 * 16];
    }

#pragma unroll
    for (int g = 0; g < 8; ++g) {
        const int cb_ = g & 1, nb_ = cb_ ^ 1;
        const int gn = (g + 1) & 7;  // wraps on last iter (harmless re-read)
#pragma unroll
        for (int t2 = 0; t2 < 2; ++t2) {
            const size_t off = (size_t)((gn * 2 + t2) * 16) * DD;
            bb[nb_][t2 * 2]     = *reinterpret_cast<const bf16x8*>(bp + off);
            bb[nb_][t2 * 2 + 1] = *reinterpret_cast<const bf16x8*>(bp + off + 32);
            cn[nb_][t2] = cnp[(gn * 2 + t2) * 16];
        }
#pragma unroll
        for (int t2 = 0; t2 < 2; ++t2) {
            const int jt = g * 2 + t2;
            f32x4 acc0 = {0.f, 0.f, 0.f, 0.f};
            f32x4 acc1 = {0.f, 0.f, 0.f, 0.f};
            acc0 = __builtin_amdgcn_mfma_f32_16x16x32_bf16(a00, bb[cb_][t2 * 2], acc0, 0, 0, 0);
            acc0 = __builtin_amdgcn_mfma_f32_16x16x32_bf16(a01, bb[cb_][t2 * 2 + 1], acc0, 0, 0, 0);
            acc1 = __builtin_amdgcn_mfma_f32_16x16x32_bf16(a10, bb[cb_][t2 * 2], acc1, 0, 0, 0);
            acc1 = __builtin_amdgcn_mfma_f32_16x16x32_bf16(a11, bb[cb_][t2 * 2 + 1], acc1, 0, 0, 0);
            const float cnt = cn[cb_][t2];
            const unsigned int jc = (unsigned int)(jt * 16 + col);  // 8-bit local idx
#pragma unroll
            for (int r = 0; r < 4; ++r) {
                float d0 = fmaf(-2.0f, acc0[r], cnt);
                unsigned int u0 = (__float_as_uint(d0) & ~255u) | jc;
                minu[r] = minu[r] < u0 ? minu[r] : u0;
                float d1 = fmaf(-2.0f, acc1[r], cnt);
                unsigned int u1 = (__float_as_uint(d1) & ~255u) | jc;
                minu[4 + r] = minu[4 + r] < u1 ? minu[4 + r] : u1;
            }
        }
    }

    // 16-col butterfly per quad: single umin per step (index rides in low bits,
    // so equal-dist ties resolve to the lowest code index automatically).
#pragma unroll
    for (int s = 0; s < 8; ++s) {
        unsigned int v = minu[s];
#pragma unroll
        for (int off = 1; off < 16; off <<= 1) {
            unsigned int ov = (unsigned int)__shfl_xor((int)v, off);
            v = v < ov ? v : ov;
        }
        if (col == 0) {
            const int rloc = (s >> 2) * 16 + quad * 4 + (s & 3);
            mg[rloc * 4 + w] = v;
        }
    }
    __syncthreads();

    // Merge the 4 code-quarters per row; strict '<' keeps the lowest quarter on tie.
    if (tid < 32) {
        unsigned int best = mg[tid * 4 + 0];
        unsigned int bestd = best & ~255u;
        int j = (int)(best & 255u);
#pragma unroll
        for (int q = 1; q < 4; ++q) {
            unsigned int uq = mg[tid * 4 + q];
            unsigned int dq = uq & ~255u;
            if (dq < bestd) { bestd = dq; j = q * 256 + (int)(uq & 255u); }
        }
        min_idx[nbase + tid] = j;
        atomicAdd(&counts[j], 1u);
    }
}

// ---------------------------------------------------------------------------
// Kernel 3: exact fp32 norms, noise injection, NCHW output; block 0 also
// computes the perplexity from the (already final) histogram.
// ---------------------------------------------------------------------------
__global__ __launch_bounds__(256) void k_out(const float* __restrict__ inp,
                                             const float* __restrict__ cb,
                                             const float* __restrict__ noise,
                                             const int* __restrict__ min_idx,
                                             const unsigned int* __restrict__ counts,
                                             float* __restrict__ out) {
    __shared__ __align__(16) float xs[64 * 64];   // [d][nl]
    __shared__ __align__(16) float ns[64 * 68];   // [nl][d], padded stride 68
    __shared__ float sscale[64];
    __shared__ float pred[4];

    const int tid = threadIdx.x;
    const int nbase = blockIdx.x * 64;
    const int b = nbase >> 10;
    const int hwbase = nbase & 1023;
    const float* xg = inp + (size_t)b * (DD * HW) + hwbase;

#pragma unroll
    for (int i = 0; i < 16; ++i) {
        int idx = i * 256 + tid;  // = d*64 + nl
        xs[idx] = xg[(idx >> 6) * HW + (idx & 63)];
    }
#pragma unroll
    for (int i = 0; i < 16; ++i) {
        int idx = i * 256 + tid;
        int nl = idx >> 6, d = idx & 63;
        ns[nl * 68 + d] = noise[(size_t)(nbase + nl) * DD + d];  // coalesced
    }
    __syncthreads();

    const int nl = tid >> 2;
    const int q = tid & 3;
    const int j = min_idx[nbase + nl];
    const float* cr = cb + (size_t)j * DD;
    float sb = 0.0f, sn = 0.0f;
#pragma unroll
    for (int dd = 0; dd < 16; ++dd) {
        int d = q * 16 + dd;
        float xv = xs[d * 64 + nl];
        float cv = cr[d];
        float nv = ns[nl * 68 + d];
        float diff = xv - cv;
        sb = fmaf(diff, diff, sb);
        sn = fmaf(nv, nv, sn);
    }
    sb += __shfl_xor(sb, 1); sb += __shfl_xor(sb, 2);
    sn += __shfl_xor(sn, 1); sn += __shfl_xor(sn, 2);
    if (q == 0) sscale[nl] = sqrtf(sb) / sqrtf(sn) + EPS_F;
    __syncthreads();

#pragma unroll
    for (int i = 0; i < 16; ++i) {
        int idx = i * 256 + tid;  // = d*64 + nl
        int d = idx >> 6, nl2 = idx & 63;
        out[(size_t)(b * DD + d) * HW + hwbase + nl2] =
            xs[idx] + sscale[nl2] * ns[nl2 * 68 + d];
    }

    // Fused perplexity (histogram is final before this kernel launches)
    if (blockIdx.x == 0) {
        float t = 0.0f;
#pragma unroll
        for (int i = 0; i < 4; ++i) {
            float p = (float)counts[tid * 4 + i] * (1.0f / (float)NN);
            t += p * logf(p + PERP_EPS_F);
        }
#pragma unroll
        for (int off = 32; off > 0; off >>= 1) t += __shfl_down(t, off);
        if ((tid & 63) == 0) pred[tid >> 6] = t;
        __syncthreads();
        if (tid == 0) out[NQ] = expf(-(pred[0] + pred[1] + pred[2] + pred[3]));
    }
}

// ---------------------------------------------------------------------------
extern "C" void kernel_launch(void* const* d_in, const int* in_sizes, int n_in,
                              void* d_out, int out_size, void* d_ws, size_t ws_size,
                              hipStream_t stream) {
    (void)in_sizes; (void)n_in; (void)out_size; (void)ws_size;
    const float* inp   = (const float*)d_in[0];   // (B,D,H,W)
    const float* cb    = (const float*)d_in[1];   // (K,D)
    const float* noise = (const float*)d_in[2];   // (N,D)
    float* out = (float*)d_out;                   // [NQ quantized][1 perplexity]

    char* ws = (char*)d_ws;
    float*          cnorm   = (float*)ws;                          // 4 KB
    int*            min_idx = (int*)(ws + 4096);                   // 128 KB
    unsigned int*   counts  = (unsigned int*)(ws + 4096 + 131072); // 4 KB
    unsigned short* cbh     = (unsigned short*)(ws + 4096 + 131072 + 4096);  // 128 KB

    k_prep<<<KK / 256, 256, 0, stream>>>(cb, cbh, cnorm, counts);
    k_argmin<<<NN / 32, 256, 0, stream>>>(inp, cbh, cnorm, min_idx, counts);
    k_out<<<NN / 64, 256, 0, stream>>>(inp, cb, noise, min_idx, counts, out);
}

// Round 4
// 103.896 us; speedup vs baseline: 1.7034x; 1.0324x over previous
//
#include <hip/hip_runtime.h>
#include <hip/hip_bf16.h>
#include <math.h>

// Problem constants (from reference setup_inputs)
#define BB 32
#define DD 64
#define HH 32
#define WW 32
#define NN (BB * HH * WW)       // 32768 rows
#define KK 1024                 // codes
#define HW (HH * WW)            // 1024
#define NQ (BB * DD * HH * WW)  // 2097152 quantized elements

#define EPS_F 1e-12f
#define PERP_EPS_F 1e-10f
#define DIST_BIAS 512.0f        // makes dist strictly positive -> uint-monotonic

typedef __attribute__((ext_vector_type(8))) __bf16 bf16x8;
typedef __attribute__((ext_vector_type(8))) unsigned short u16x8;
typedef __attribute__((ext_vector_type(4))) float f32x4;

// fp32 -> bf16 round-to-nearest-even, bit-level
static __device__ __forceinline__ unsigned short f2bf(float f) {
    union { float f; unsigned int u; } c;
    c.f = f;
    unsigned int r = c.u + 0x7FFFu + ((c.u >> 16) & 1u);
    return (unsigned short)(r >> 16);
}

// ---------------------------------------------------------------------------
// Kernel 1: codes fp32 -> bf16 + (||c||^2 + 512) + zero the histogram.
// 16 blocks x 256 threads; one quarter-row (16 elems) per thread.
// ---------------------------------------------------------------------------
__global__ __launch_bounds__(256) void k_prep(const float* __restrict__ cb,
                                              unsigned short* __restrict__ cbh,
                                              float* __restrict__ cnorm,
                                              unsigned int* __restrict__ counts) {
    const int gt = blockIdx.x * 256 + threadIdx.x;  // 0..4095
    const int j = gt >> 2;
    const int q = gt & 3;
    const float4* src = reinterpret_cast<const float4*>(cb + (size_t)j * DD + q * 16);
    ushort4* dst = reinterpret_cast<ushort4*>(cbh + (size_t)j * DD + q * 16);
    float s = 0.0f;
#pragma unroll
    for (int i = 0; i < 4; ++i) {
        float4 v = src[i];
        s += v.x * v.x + v.y * v.y + v.z * v.z + v.w * v.w;
        ushort4 u;
        u.x = f2bf(v.x); u.y = f2bf(v.y); u.z = f2bf(v.z); u.w = f2bf(v.w);
        dst[i] = u;
    }
    // reduce the 4 quarter-norms (q lives in lane bits 0..1)
    s += __shfl_xor(s, 1);
    s += __shfl_xor(s, 2);
    if (q == 0) {
        cnorm[j] = s + DIST_BIAS;
        counts[j] = 0u;
    }
}

// ---------------------------------------------------------------------------
// Kernel 2 (fused): MFMA argmin + exact fp32 norms + noise injection + NCHW
// output + histogram. 1024 blocks x 256 threads (4 waves/SIMD). Block owns
// 32 rows; wave w computes all 32 rows x codes [w*256, +256). B-frags stream
// from global bf16 codes (L2-resident), double-buffered. Argmin carried as
// packed u32: (bits(dist+512) & ~255) | local_code_idx.
// ---------------------------------------------------------------------------
__global__ __launch_bounds__(256) void k_main(const float* __restrict__ inp,
                                              const unsigned short* __restrict__ cbh,
                                              const float* __restrict__ cb,
                                              const float* __restrict__ cnorm,
                                              const float* __restrict__ noise,
                                              unsigned int* __restrict__ counts,
                                              float* __restrict__ out) {
    __shared__ __align__(16) unsigned short xls[32 * 72];  // bf16 [r][d], stride 72
    __shared__ float xs[64 * 33];   // fp32 x, [d][r] stride 33: bank=(d+r)%32
    __shared__ float ns[64 * 33];   // noise,   [d][r] stride 33 (stored transposed)
    __shared__ unsigned int mg[32 * 4];  // winner per [row][quarter]
    __shared__ int jwin[32];
    __shared__ float sscale[32];

    const int tid = threadIdx.x;
    const int nbase = blockIdx.x * 32;
    const int b = nbase >> 10;        // 32 | 1024: no batch/HW crossing
    const int hwbase = nbase & 1023;
    const float* xg = inp + (size_t)b * (DD * HW) + hwbase;

    const int rr = tid >> 3;   // row 0..31   (per-row phases)
    const int qq = tid & 7;    // octet 0..7  (8 dims each; lane bits 0..2)

    // Prefetch this thread's noise chunk (held in regs through the argmin phase)
    const float4 nz0 = *reinterpret_cast<const float4*>(noise + (size_t)(nbase + rr) * DD + qq * 8);
    const float4 nz1 = *reinterpret_cast<const float4*>(noise + (size_t)(nbase + rr) * DD + qq * 8 + 4);

    // Stage x fp32: global [d][hw] -> coalesced; LDS [d][r] stride 33.
#pragma unroll
    for (int i = 0; i < 8; ++i) {
        int idx = i * 256 + tid;  // = d*32 + r
        int d = idx >> 5, r = idx & 31;
        xs[d * 33 + r] = xg[d * HW + r];
    }
    __syncthreads();

    // Build bf16 A-tile [r][d] from the fp32 LDS copy (2-way reads, free).
    {
        u16x8 pk;
#pragma unroll
        for (int j2 = 0; j2 < 8; ++j2)
            pk[j2] = f2bf(xs[(qq * 8 + j2) * 33 + rr]);
        *reinterpret_cast<u16x8*>(&xls[rr * 72 + qq * 8]) = pk;
    }
    __syncthreads();

    const int lane = tid & 63;
    const int w = tid >> 6;        // wave id = code quarter
    const int col = lane & 15;
    const int quad = lane >> 4;

    // A fragments: A[m=lane&15][k=quad*8+j]; 2 row-tiles x 2 k-halves.
    const bf16x8 a00 = *reinterpret_cast<const bf16x8*>(&xls[col * 72 + quad * 8]);
    const bf16x8 a01 = *reinterpret_cast<const bf16x8*>(&xls[col * 72 + 32 + quad * 8]);
    const bf16x8 a10 = *reinterpret_cast<const bf16x8*>(&xls[(16 + col) * 72 + quad * 8]);
    const bf16x8 a11 = *reinterpret_cast<const bf16x8*>(&xls[(16 + col) * 72 + 32 + quad * 8]);

    unsigned int minu[8];
#pragma unroll
    for (int s = 0; s < 8; ++s) minu[s] = 0xFFFFFFFFu;

    // B lane base: code row (w*256 + jt*16 + col), 8 contiguous d per quad.
    const unsigned short* bp = cbh + (size_t)(w * 256 + col) * DD + quad * 8;
    const float* cnp = cnorm + w * 256 + col;

    bf16x8 bb[2][4];
    float cn[2][2];
#pragma unroll
    for (int t2 = 0; t2 < 2; ++t2) {
        bb[0][t2 * 2]     = *reinterpret_cast<const bf16x8*>(bp + (size_t)(t2 * 16) * DD);
        bb[0][t2 * 2 + 1] = *reinterpret_cast<const bf16x8*>(bp + (size_t)(t2 * 16) * DD + 32);
        cn[0][t2] = cnp[t2 * 16];
    }

#pragma unroll
    for (int g = 0; g < 8; ++g) {
        const int cb_ = g & 1, nb_ = cb_ ^ 1;
        const int gn = (g + 1) & 7;  // wraps on last iter (harmless re-read)
#pragma unroll
        for (int t2 = 0; t2 < 2; ++t2) {
            const size_t off = (size_t)((gn * 2 + t2) * 16) * DD;
            bb[nb_][t2 * 2]     = *reinterpret_cast<const bf16x8*>(bp + off);
            bb[nb_][t2 * 2 + 1] = *reinterpret_cast<const bf16x8*>(bp + off + 32);
            cn[nb_][t2] = cnp[(gn * 2 + t2) * 16];
        }
#pragma unroll
        for (int t2 = 0; t2 < 2; ++t2) {
            const int jt = g * 2 + t2;
            f32x4 acc0 = {0.f, 0.f, 0.f, 0.f};
            f32x4 acc1 = {0.f, 0.f, 0.f, 0.f};
            acc0 = __builtin_amdgcn_mfma_f32_16x16x32_bf16(a00, bb[cb_][t2 * 2], acc0, 0, 0, 0);
            acc0 = __builtin_amdgcn_mfma_f32_16x16x32_bf16(a01, bb[cb_][t2 * 2 + 1], acc0, 0, 0, 0);
            acc1 = __builtin_amdgcn_mfma_f32_16x16x32_bf16(a10, bb[cb_][t2 * 2], acc1, 0, 0, 0);
            acc1 = __builtin_amdgcn_mfma_f32_16x16x32_bf16(a11, bb[cb_][t2 * 2 + 1], acc1, 0, 0, 0);
            const float cnt = cn[cb_][t2];
            const unsigned int jc = (unsigned int)(jt * 16 + col);  // 8-bit local idx
#pragma unroll
            for (int r = 0; r < 4; ++r) {
                float d0 = fmaf(-2.0f, acc0[r], cnt);
                unsigned int u0 = (__float_as_uint(d0) & ~255u) | jc;
                minu[r] = minu[r] < u0 ? minu[r] : u0;
                float d1 = fmaf(-2.0f, acc1[r], cnt);
                unsigned int u1 = (__float_as_uint(d1) & ~255u) | jc;
                minu[4 + r] = minu[4 + r] < u1 ? minu[4 + r] : u1;
            }
        }
    }

    // 16-col butterfly per quad; index rides in the low bits, so ties resolve
    // to the lowest code index automatically.
#pragma unroll
    for (int s = 0; s < 8; ++s) {
        unsigned int v = minu[s];
#pragma unroll
        for (int off = 1; off < 16; off <<= 1) {
            unsigned int ov = (unsigned int)__shfl_xor((int)v, off);
            v = v < ov ? v : ov;
        }
        if (col == 0) {
            const int rloc = (s >> 2) * 16 + quad * 4 + (s & 3);
            mg[rloc * 4 + w] = v;
        }
    }
    __syncthreads();

    // Merge the 4 code-quarters per row; strict '<' keeps the lowest quarter on tie.
    if (tid < 32) {
        unsigned int best = mg[tid * 4 + 0];
        unsigned int bestd = best & ~255u;
        int j = (int)(best & 255u);
#pragma unroll
        for (int q = 1; q < 4; ++q) {
            unsigned int uq = mg[tid * 4 + q];
            unsigned int dq = uq & ~255u;
            if (dq < bestd) { bestd = dq; j = q * 256 + (int)(uq & 255u); }
        }
        jwin[tid] = j;
        atomicAdd(&counts[j], 1u);
    }
    __syncthreads();

    // Exact fp32 norms from the gathered winner; 8 lanes cooperate per row.
    {
        const int j = jwin[rr];
        const float* cr = cb + (size_t)j * DD + qq * 8;
        const float4 c0 = *reinterpret_cast<const float4*>(cr);
        const float4 c1 = *reinterpret_cast<const float4*>(cr + 4);
        float xv[8];
#pragma unroll
        for (int j2 = 0; j2 < 8; ++j2) xv[j2] = xs[(qq * 8 + j2) * 33 + rr];
        float sb = 0.0f, sn = 0.0f;
        float df;
        df = xv[0] - c0.x; sb = fmaf(df, df, sb); sn = fmaf(nz0.x, nz0.x, sn);
        df = xv[1] - c0.y; sb = fmaf(df, df, sb); sn = fmaf(nz0.y, nz0.y, sn);
        df = xv[2] - c0.z; sb = fmaf(df, df, sb); sn = fmaf(nz0.z, nz0.z, sn);
        df = xv[3] - c0.w; sb = fmaf(df, df, sb); sn = fmaf(nz0.w, nz0.w, sn);
        df = xv[4] - c1.x; sb = fmaf(df, df, sb); sn = fmaf(nz1.x, nz1.x, sn);
        df = xv[5] - c1.y; sb = fmaf(df, df, sb); sn = fmaf(nz1.y, nz1.y, sn);
        df = xv[6] - c1.z; sb = fmaf(df, df, sb); sn = fmaf(nz1.z, nz1.z, sn);
        df = xv[7] - c1.w; sb = fmaf(df, df, sb); sn = fmaf(nz1.w, nz1.w, sn);
        // reduce over qq (lane bits 0..2)
        sb += __shfl_xor(sb, 1); sb += __shfl_xor(sb, 2); sb += __shfl_xor(sb, 4);
        sn += __shfl_xor(sn, 1); sn += __shfl_xor(sn, 2); sn += __shfl_xor(sn, 4);
        if (qq == 0) sscale[rr] = sqrtf(sb) / sqrtf(sn) + EPS_F;
        // park noise transposed for the coalesced write phase (2-way writes, free)
        ns[(qq * 8 + 0) * 33 + rr] = nz0.x;
        ns[(qq * 8 + 1) * 33 + rr] = nz0.y;
        ns[(qq * 8 + 2) * 33 + rr] = nz0.z;
        ns[(qq * 8 + 3) * 33 + rr] = nz0.w;
        ns[(qq * 8 + 4) * 33 + rr] = nz1.x;
        ns[(qq * 8 + 5) * 33 + rr] = nz1.y;
        ns[(qq * 8 + 6) * 33 + rr] = nz1.z;
        ns[(qq * 8 + 7) * 33 + rr] = nz1.w;
    }
    __syncthreads();

    // quantized = x + scale*noise, NCHW-coalesced writes.
#pragma unroll
    for (int i = 0; i < 8; ++i) {
        int idx = i * 256 + tid;  // = d*32 + r
        int d = idx >> 5, r = idx & 31;
        out[(size_t)(b * DD + d) * HW + hwbase + r] =
            xs[d * 33 + r] + sscale[r] * ns[d * 33 + r];
    }
}

// ---------------------------------------------------------------------------
// Kernel 3: perplexity from the completed histogram. One block, 1024 threads.
// ---------------------------------------------------------------------------
__global__ __launch_bounds__(1024) void k_perp(const unsigned int* __restrict__ counts,
                                               float* __restrict__ out) {
    __shared__ float red[16];
    const int tid = threadIdx.x;
    const int lane = tid & 63;
    float p = (float)counts[tid] * (1.0f / (float)NN);
    float t = p * logf(p + PERP_EPS_F);
#pragma unroll
    for (int off = 32; off > 0; off >>= 1) t += __shfl_down(t, off);
    if (lane == 0) red[tid >> 6] = t;
    __syncthreads();
    if (tid == 0) {
        float s = 0.0f;
#pragma unroll
        for (int i = 0; i < 16; ++i) s += red[i];
        out[0] = expf(-s);
    }
}

// ---------------------------------------------------------------------------
extern "C" void kernel_launch(void* const* d_in, const int* in_sizes, int n_in,
                              void* d_out, int out_size, void* d_ws, size_t ws_size,
                              hipStream_t stream) {
    (void)in_sizes; (void)n_in; (void)out_size; (void)ws_size;
    const float* inp   = (const float*)d_in[0];   // (B,D,H,W)
    const float* cb    = (const float*)d_in[1];   // (K,D)
    const float* noise = (const float*)d_in[2];   // (N,D)
    float* out = (float*)d_out;                   // [NQ quantized][1 perplexity]

    char* ws = (char*)d_ws;
    float*          cnorm  = (float*)ws;                  // 4 KB
    unsigned int*   counts = (unsigned int*)(ws + 4096);  // 4 KB
    unsigned short* cbh    = (unsigned short*)(ws + 8192);// 128 KB

    k_prep<<<16, 256, 0, stream>>>(cb, cbh, cnorm, counts);
    k_main<<<NN / 32, 256, 0, stream>>>(inp, cbh, cb, cnorm, noise, counts, out);
    k_perp<<<1, 1024, 0, stream>>>(counts, out + NQ);
}